// Round 7
// baseline (577.232 us; speedup 1.0000x reference)
//
#include <hip/hip_runtime.h>
#include <cstdint>
#include <cstddef>

typedef __attribute__((ext_vector_type(8))) short short8;
typedef __attribute__((ext_vector_type(4))) float f32x4;
typedef __attribute__((ext_vector_type(4))) unsigned short us4;

#define GAS(p) ((const __attribute__((address_space(1))) void*)(p))
#define LAS(p) ((__attribute__((address_space(3))) void*)(p))

__device__ __forceinline__ unsigned short f2bf(float f) {
  union { float f; unsigned u; } v; v.f = f;
  return (unsigned short)((v.u + 0x7fffu + ((v.u >> 16) & 1u)) >> 16);
}

// ---------- fp32 -> bf16 convert (x4 vectorized) ----------
__global__ __launch_bounds__(256) void cvt_kernel(const float* __restrict__ in,
                                                  unsigned short* __restrict__ out, int n4) {
  int i = blockIdx.x * 256 + threadIdx.x;
  if (i >= n4) return;
  f32x4 v = ((const f32x4*)in)[i];
  us4 o;
#pragma unroll
  for (int j = 0; j < 4; ++j) o[j] = f2bf(v[j]);
  ((us4*)out)[i] = o;
}

// ---------- LayerNorm: one wave per row of 768, bf16 out ----------
__global__ __launch_bounds__(256) void ln_kernel(const float* __restrict__ x,
                                                 const float* __restrict__ g,
                                                 const float* __restrict__ b,
                                                 unsigned short* __restrict__ out) {
  const int wave = threadIdx.x >> 6, lane = threadIdx.x & 63;
  const int row = blockIdx.x * 4 + wave;
  const float* xr = x + (size_t)row * 768;
  f32x4 v[3];
  float s = 0.f, sq = 0.f;
#pragma unroll
  for (int c = 0; c < 3; ++c) {
    v[c] = *(const f32x4*)(xr + c * 256 + lane * 4);
#pragma unroll
    for (int j = 0; j < 4; ++j) { s += v[c][j]; sq += v[c][j] * v[c][j]; }
  }
#pragma unroll
  for (int off = 32; off > 0; off >>= 1) { s += __shfl_xor(s, off); sq += __shfl_xor(sq, off); }
  const float mu = s * (1.f / 768.f);
  const float var = sq * (1.f / 768.f) - mu * mu;
  const float rs = rsqrtf(var + 1e-5f);
  unsigned short* orow = out + (size_t)row * 768;
#pragma unroll
  for (int c = 0; c < 3; ++c) {
    f32x4 gg = *(const f32x4*)(g + c * 256 + lane * 4);
    f32x4 bb = *(const f32x4*)(b + c * 256 + lane * 4);
    us4 o;
#pragma unroll
    for (int j = 0; j < 4; ++j) o[j] = f2bf((v[c][j] - mu) * rs * gg[j] + bb[j]);
    *(us4*)(orow + c * 256 + lane * 4) = o;
  }
}

// ---------- GEMM: C[M,NN] = A[M,K](bf16) @ W[NN,K]^T(bf16) ----------
// 256x256 tile, 512 threads (8 waves, 2Mx4N), BK=64, double-buffered LDS.
// ONE barrier + one vmcnt(0) per K-tile; loads for tile t+1 issued right after
// the tile-t barrier (a full K-tile ahead -> vmcnt(0) waits on ~2500-cyc-old
// loads = free). No intra-tile barriers: 4 free-running {ds_read -> 16 MFMA}
// clusters per wave so LDS and matrix pipes overlap across waves. XOR-swizzled
// LDS (chunk ^ row&7, verified 0-conflict pattern), bijective XCD swizzle,
// setprio around MFMA clusters.
// EPI 0: qkv scatter -> q (prescaled by 0.125), k [B,H,N,64], vt [B,H,64,N]
// EPI 1: outF = acc + bias[col] + res[idx]   (fp32)
// EPI 2: outU = bf16(gelu_tanh(acc + bias[col]))
template <int EPI, int NN, int K>
__global__ __launch_bounds__(512, 2) void gemm64(
    const unsigned short* __restrict__ A, const unsigned short* __restrict__ W,
    float* __restrict__ outF, const float* __restrict__ bias, const float* __restrict__ res,
    unsigned short* __restrict__ outU,
    unsigned short* __restrict__ q, unsigned short* __restrict__ kk, unsigned short* __restrict__ vt) {
  __shared__ unsigned short As[2 * 16384];   // [buf][256 rows x 64 ushorts (128B)]
  __shared__ unsigned short Bs[2 * 16384];
  const int tid = threadIdx.x;
  const int wave = tid >> 6, lane = tid & 63;
  const int lr = lane & 15, lg = lane >> 4;
  const int wr = wave >> 2, wc = wave & 3;
  constexpr int GX = NN / 256;
  constexpr int NWG = GX * 64;               // M=16384 -> 64 row tiles; NWG % 8 == 0
  int id = blockIdx.y * GX + blockIdx.x;
  id = (id & 7) * (NWG / 8) + (id >> 3);     // bijective XCD swizzle
  const int row0 = (id / GX) * 256, col0 = (id % GX) * 256;
  f32x4 acc[8][4] = {};
  // staging: issue i covers 64 rows; thread t -> row i*64+(t>>3), LDS chunk t&7
  // (linear dest = wave-uniform base + lane*16B); global chunk pre-swizzled
  // with ^((t>>3)&7) so LDS[row][c] holds global chunk c ^ (row&7).
  const unsigned short* ag = A + (size_t)(row0 + (tid >> 3)) * K + (((tid & 7) ^ ((tid >> 3) & 7)) * 8);
  const unsigned short* bg = W + (size_t)(col0 + (tid >> 3)) * K + (((tid & 7) ^ ((tid >> 3) & 7)) * 8);
  const int KT = K / 64;                     // 12 (K=768) or 48 (K=3072)

#define STG64(buf, t_)                                                                         \
  {                                                                                            \
    const unsigned short* a0 = ag + (t_) * 64;                                                 \
    const unsigned short* b0 = bg + (t_) * 64;                                                 \
    _Pragma("unroll")                                                                          \
    for (int i = 0; i < 4; ++i) {                                                              \
      __builtin_amdgcn_global_load_lds(GAS(a0 + (size_t)(i * 64) * K),                         \
                                       LAS(&As[(buf) * 16384 + i * 4096 + wave * 512]), 16, 0, 0); \
      __builtin_amdgcn_global_load_lds(GAS(b0 + (size_t)(i * 64) * K),                         \
                                       LAS(&Bs[(buf) * 16384 + i * 4096 + wave * 512]), 16, 0, 0); \
    }                                                                                          \
  }

#define TILE64(buf, t_)                                                                        \
  {                                                                                            \
    asm volatile("s_waitcnt vmcnt(0)" ::: "memory");                                           \
    __builtin_amdgcn_s_barrier();                                                              \
    if ((t_) + 1 < KT) STG64((buf) ^ 1, (t_) + 1);                                             \
    const char* Abase = (const char*)As + (buf) * 32768;                                       \
    const char* Bbase = (const char*)Bs + (buf) * 32768;                                       \
    _Pragma("unroll")                                                                          \
    for (int kb = 0; kb < 2; ++kb) {                                                           \
      short8 af[8];                                                                            \
      _Pragma("unroll")                                                                        \
      for (int m = 0; m < 8; ++m) {                                                            \
        const int arow = wr * 128 + m * 16 + lr;                                               \
        af[m] = *(const short8*)(Abase + arow * 128 + ((kb * 64 + lg * 16) ^ ((arow & 7) << 4))); \
      }                                                                                        \
      _Pragma("unroll")                                                                        \
      for (int nh = 0; nh < 2; ++nh) {                                                         \
        short8 bf0, bf1;                                                                       \
        {                                                                                      \
          const int brow0 = wc * 64 + (nh * 2) * 16 + lr;                                      \
          const int brow1 = brow0 + 16;                                                        \
          bf0 = *(const short8*)(Bbase + brow0 * 128 + ((kb * 64 + lg * 16) ^ ((brow0 & 7) << 4))); \
          bf1 = *(const short8*)(Bbase + brow1 * 128 + ((kb * 64 + lg * 16) ^ ((brow1 & 7) << 4))); \
        }                                                                                      \
        __builtin_amdgcn_s_setprio(1);                                                         \
        _Pragma("unroll")                                                                      \
        for (int m = 0; m < 8; ++m) {                                                          \
          acc[m][nh * 2]     = __builtin_amdgcn_mfma_f32_16x16x32_bf16(af[m], bf0, acc[m][nh * 2], 0, 0, 0); \
          acc[m][nh * 2 + 1] = __builtin_amdgcn_mfma_f32_16x16x32_bf16(af[m], bf1, acc[m][nh * 2 + 1], 0, 0, 0); \
        }                                                                                      \
        __builtin_amdgcn_s_setprio(0);                                                         \
      }                                                                                        \
    }                                                                                          \
  }

  // prologue: stage tile 0 into buf 0
  STG64(0, 0);
  for (int tt = 0; tt < KT; tt += 2) {
    TILE64(0, tt);
    TILE64(1, tt + 1);
  }
#undef TILE64
#undef STG64

#pragma unroll
  for (int m = 0; m < 8; ++m)
#pragma unroll
    for (int n = 0; n < 4; ++n)
#pragma unroll
      for (int r = 0; r < 4; ++r) {
        const int grow = row0 + wr * 128 + m * 16 + lg * 4 + r;
        const int gcol = col0 + wc * 64 + n * 16 + lr;
        const float val = acc[m][n][r];
        if (EPI == 0) {
          const int s = gcol / 768;
          const int rem = gcol - s * 768;
          const int hh = rem >> 6, d = rem & 63;
          const int bt = grow >> 10, nt = grow & 1023;
          const size_t bh = (size_t)(bt * 12 + hh);
          if (s == 0)      q[(bh * 1024 + nt) * 64 + d] = f2bf(val * 0.125f);
          else if (s == 1) kk[(bh * 1024 + nt) * 64 + d] = f2bf(val);
          else             vt[(bh * 64 + d) * 1024 + nt] = f2bf(val);
        } else if (EPI == 1) {
          const size_t idx = (size_t)grow * NN + gcol;
          outF[idx] = val + bias[gcol] + res[idx];
        } else {
          const size_t idx = (size_t)grow * NN + gcol;
          const float t = val + bias[gcol];
          // tanh-form GELU (max err ~1e-3 vs exact erf form)
          float u = 0.7978845608f * (t + 0.044715f * t * t * t);
          u = fminf(fmaxf(u, -10.f), 10.f);
          const float e = __expf(2.f * u);
          const float th = (e - 1.f) / (e + 1.f);
          outU[idx] = f2bf(0.5f * t * (1.f + th));
        }
      }
}

// ---------- Flash attention, swapped-operand (S^T / O^T), in-register softmax ----------
// block = (qtile of 128, head, batch), 4 waves x 32 q-rows; KV tiles of 64,
// depth-2 pipeline with counted vmcnt + raw barriers.
__global__ __launch_bounds__(256) void attn_kernel(
    const unsigned short* __restrict__ Q, const unsigned short* __restrict__ K,
    const unsigned short* __restrict__ V, unsigned short* __restrict__ O) {
  __shared__ unsigned short Ks[2][64 * 64];  // [kv][d], chunk-swizzled rows
  __shared__ unsigned short Vs[2][64 * 64];  // [d][kv], chunk-swizzled rows
  const int tid = threadIdx.x, wave = tid >> 6, lane = tid & 63;
  const int lr = lane & 15, lg = lane >> 4;
  const int qt = blockIdx.x, hh = blockIdx.y, bb = blockIdx.z;
  const size_t bh = (size_t)bb * 12 + hh;
  const unsigned short* Qg = Q + bh * 1024 * 64;
  const unsigned short* Kg = K + bh * 1024 * 64;
  const unsigned short* Vg = V + bh * 64 * 1024;
  const int q0 = qt * 128 + wave * 32;
  // Q fragments (Q already prescaled by 0.125 at QKV epilogue)
  short8 aq[2][2];  // [nq][kb]
#pragma unroll
  for (int nq = 0; nq < 2; ++nq)
#pragma unroll
    for (int kb = 0; kb < 2; ++kb)
      aq[nq][kb] = *(const short8*)(Qg + (size_t)(q0 + nq * 16 + lr) * 64 + kb * 32 + lg * 8);
  float m_run[2] = {-1e30f, -1e30f}, l_run[2] = {0.f, 0.f};
  f32x4 oacc[4][2] = {};  // [mb over d][nq], O^T layout: col=q(lr), row=d
  const int srow = tid >> 3;                                      // staging row 0..31
  const int sswz = (((tid & 7) * 16) ^ ((srow & 7) << 4)) >> 1;   // pre-swizzled src (ushort)
  const int srcLo = (lane & 15) | ((lane & 16) << 1);             // lr + 32*(lg&1)
  const int srcHi = srcLo + 16;
  const bool hiSel = lg >= 2;
#define ATTN_STAGE(buf, t_)                                                                      \
  {                                                                                              \
    const int kv_ = (t_) * 64;                                                                   \
    _Pragma("unroll")                                                                            \
    for (int is = 0; is < 2; ++is) {                                                             \
      __builtin_amdgcn_global_load_lds(GAS(Kg + (size_t)(kv_ + is * 32 + srow) * 64 + sswz),     \
                                       LAS(&Ks[buf][is * 2048 + wave * 512]), 16, 0, 0);         \
      __builtin_amdgcn_global_load_lds(GAS(Vg + (size_t)(is * 32 + srow) * 1024 + kv_ + sswz),   \
                                       LAS(&Vs[buf][is * 2048 + wave * 512]), 16, 0, 0);         \
    }                                                                                            \
  }
  // prologue: stage tiles 0 and 1
  ATTN_STAGE(0, 0);
  ATTN_STAGE(1, 1);
  for (int t = 0; t < 16; ++t) {
    const int cur = t & 1;
    if (t < 15) asm volatile("s_waitcnt vmcnt(4)" ::: "memory");
    else        asm volatile("s_waitcnt vmcnt(0)" ::: "memory");
    __builtin_amdgcn_s_barrier();        // tile t ready in buf[cur]
    __builtin_amdgcn_sched_barrier(0);
    // S^T[kv][q] = mfma(K rows, Q rows)
    f32x4 sacc[4][2] = {};  // [mk][nq]; lane: col q = nq*16+lr, rows kv = mk*16+lg*4+r
#pragma unroll
    for (int kb = 0; kb < 2; ++kb) {
      short8 kf[4];
#pragma unroll
      for (int mk = 0; mk < 4; ++mk) {
        const int row = mk * 16 + lr;
        const int boff = row * 128 + ((kb * 64 + lg * 16) ^ ((row & 7) << 4));
        kf[mk] = *(const short8*)((const char*)&Ks[cur][0] + boff);
      }
#pragma unroll
      for (int mk = 0; mk < 4; ++mk)
#pragma unroll
        for (int nq = 0; nq < 2; ++nq)
          sacc[mk][nq] = __builtin_amdgcn_mfma_f32_16x16x32_bf16(kf[mk], aq[nq][kb], sacc[mk][nq], 0, 0, 0);
    }
    // online softmax per q column (lane-local stats, 4x duplicated across lg)
    unsigned pk[4][2][2];
#pragma unroll
    for (int nq = 0; nq < 2; ++nq) {
      float mx = sacc[0][nq][0];
#pragma unroll
      for (int mk = 0; mk < 4; ++mk)
#pragma unroll
        for (int r = 0; r < 4; ++r) mx = fmaxf(mx, sacc[mk][nq][r]);
      mx = fmaxf(mx, __shfl_xor(mx, 16));
      mx = fmaxf(mx, __shfl_xor(mx, 32));
      const float mnew = fmaxf(m_run[nq], mx);
      const float alpha = __expf(m_run[nq] - mnew);
      float ssum = 0.f;
#pragma unroll
      for (int mk = 0; mk < 4; ++mk)
#pragma unroll
        for (int r = 0; r < 4; ++r) {
          const float p = __expf(sacc[mk][nq][r] - mnew);
          sacc[mk][nq][r] = p;
          ssum += p;
        }
      ssum += __shfl_xor(ssum, 16);
      ssum += __shfl_xor(ssum, 32);
      l_run[nq] = alpha * l_run[nq] + ssum;
      m_run[nq] = mnew;
#pragma unroll
      for (int mb = 0; mb < 4; ++mb)
#pragma unroll
        for (int r = 0; r < 4; ++r) oacc[mb][nq][r] *= alpha;
      // pack P rows to bf16 pairs: pk[mk][nq] = {bf(p0),bf(p1)},{bf(p2),bf(p3)}
#pragma unroll
      for (int mk = 0; mk < 4; ++mk) {
        asm("v_cvt_pk_bf16_f32 %0, %1, %2" : "=v"(pk[mk][nq][0]) : "v"(sacc[mk][nq][0]), "v"(sacc[mk][nq][1]));
        asm("v_cvt_pk_bf16_f32 %0, %1, %2" : "=v"(pk[mk][nq][1]) : "v"(sacc[mk][nq][2]), "v"(sacc[mk][nq][3]));
      }
    }
    // O^T += mfma(Vt rows, P rows); P rows assembled via cross-lane redistribution
#pragma unroll
    for (int kb = 0; kb < 2; ++kb) {
      short8 vf[4];
#pragma unroll
      for (int mb = 0; mb < 4; ++mb) {
        const int row = mb * 16 + lr;
        const int boff = row * 128 + ((kb * 64 + lg * 16) ^ ((row & 7) << 4));
        vf[mb] = *(const short8*)((const char*)&Vs[cur][0] + boff);
      }
#pragma unroll
      for (int nq = 0; nq < 2; ++nq) {
        unsigned a0 = (unsigned)__shfl((int)pk[2 * kb][nq][0], srcLo);
        unsigned b0 = (unsigned)__shfl((int)pk[2 * kb + 1][nq][0], srcLo);
        unsigned a1 = (unsigned)__shfl((int)pk[2 * kb][nq][1], srcLo);
        unsigned b1 = (unsigned)__shfl((int)pk[2 * kb + 1][nq][1], srcLo);
        unsigned a2 = (unsigned)__shfl((int)pk[2 * kb][nq][0], srcHi);
        unsigned b2 = (unsigned)__shfl((int)pk[2 * kb + 1][nq][0], srcHi);
        unsigned a3 = (unsigned)__shfl((int)pk[2 * kb][nq][1], srcHi);
        unsigned b3 = (unsigned)__shfl((int)pk[2 * kb + 1][nq][1], srcHi);
        union { unsigned u[4]; short8 s; } cvt;
        cvt.u[0] = hiSel ? b0 : a0;
        cvt.u[1] = hiSel ? b1 : a1;
        cvt.u[2] = hiSel ? b2 : a2;
        cvt.u[3] = hiSel ? b3 : a3;
        const short8 pb = cvt.s;
#pragma unroll
        for (int mb = 0; mb < 4; ++mb)
          oacc[mb][nq] = __builtin_amdgcn_mfma_f32_16x16x32_bf16(vf[mb], pb, oacc[mb][nq], 0, 0, 0);
      }
    }
    asm volatile("s_waitcnt lgkmcnt(0)" ::: "memory");
    __builtin_amdgcn_sched_barrier(0);
    __builtin_amdgcn_s_barrier();        // all waves done reading buf[cur]
    if (t + 2 < 16) ATTN_STAGE(cur, t + 2);
  }
#undef ATTN_STAGE
  // epilogue: O[tok][hh*64+d] = oacc^T / l
#pragma unroll
  for (int nq = 0; nq < 2; ++nq) {
    const float linv = 1.f / l_run[nq];
    const size_t tok = (size_t)(bb << 10) + q0 + nq * 16 + lr;
#pragma unroll
    for (int mb = 0; mb < 4; ++mb) {
      us4 o;
#pragma unroll
      for (int r = 0; r < 4; ++r) o[r] = f2bf(oacc[mb][nq][r] * linv);
      *(us4*)(O + tok * 768 + hh * 64 + mb * 16 + lg * 4) = o;
    }
  }
}

extern "C" void kernel_launch(void* const* d_in, const int* in_sizes, int n_in,
                              void* d_out, int out_size, void* d_ws, size_t ws_size,
                              hipStream_t stream) {
  const float* x      = (const float*)d_in[0];
  const float* ln1_g  = (const float*)d_in[1];
  const float* ln1_b  = (const float*)d_in[2];
  const float* qkv_w  = (const float*)d_in[3];
  const float* proj_w = (const float*)d_in[4];
  const float* proj_b = (const float*)d_in[5];
  const float* ln2_g  = (const float*)d_in[6];
  const float* ln2_b  = (const float*)d_in[7];
  const float* fc1_w  = (const float*)d_in[8];
  const float* fc1_b  = (const float*)d_in[9];
  const float* fc2_w  = (const float*)d_in[10];
  const float* fc2_b  = (const float*)d_in[11];
  float* out = (float*)d_out;
  char* ws = (char*)d_ws;

  unsigned short* wqkv = (unsigned short*)(ws + 0);
  unsigned short* wproj = (unsigned short*)(ws + 3538944);
  unsigned short* wfc1 = (unsigned short*)(ws + 4718592);
  unsigned short* wfc2 = (unsigned short*)(ws + 9437184);
  unsigned short* hbuf = (unsigned short*)(ws + 14155776);          // 16384x768 bf16
  char* big = ws + 39321600;                                        // 96 MB region
  unsigned short* qb  = (unsigned short*)(big);
  unsigned short* kb  = (unsigned short*)(big + 25165824);
  unsigned short* vtb = (unsigned short*)(big + 50331648);
  unsigned short* ob  = (unsigned short*)(big + 75497472);
  unsigned short* hid = (unsigned short*)(big);                     // reuses q/k/vt/o after attn+proj

  // weights -> bf16
  cvt_kernel<<<1728, 256, 0, stream>>>(qkv_w, wqkv, 442368);
  cvt_kernel<<<576, 256, 0, stream>>>(proj_w, wproj, 147456);
  cvt_kernel<<<2304, 256, 0, stream>>>(fc1_w, wfc1, 589824);
  cvt_kernel<<<2304, 256, 0, stream>>>(fc2_w, wfc2, 589824);

  // LN1
  ln_kernel<<<4096, 256, 0, stream>>>(x, ln1_g, ln1_b, hbuf);
  // QKV
  gemm64<0, 2304, 768><<<dim3(9, 64), 512, 0, stream>>>(
      hbuf, wqkv, nullptr, nullptr, nullptr, nullptr, qb, kb, vtb);
  // attention
  attn_kernel<<<dim3(8, 12, 16), 256, 0, stream>>>(qb, kb, vtb, ob);
  // proj + residual -> x1 (in d_out)
  gemm64<1, 768, 768><<<dim3(3, 64), 512, 0, stream>>>(
      ob, wproj, out, proj_b, x, nullptr, nullptr, nullptr, nullptr);
  // LN2
  ln_kernel<<<4096, 256, 0, stream>>>(out, ln2_g, ln2_b, hbuf);
  // FC1 + gelu
  gemm64<2, 3072, 768><<<dim3(12, 64), 512, 0, stream>>>(
      hbuf, wfc1, nullptr, fc1_b, nullptr, hid, nullptr, nullptr, nullptr);
  // FC2 + residual -> out
  gemm64<1, 768, 3072><<<dim3(3, 64), 512, 0, stream>>>(
      hid, wfc2, out, fc2_b, out, nullptr, nullptr, nullptr, nullptr);
}

// Round 8
// 557.375 us; speedup vs baseline: 1.0356x; 1.0356x over previous
//
#include <hip/hip_runtime.h>
#include <cstdint>
#include <cstddef>

typedef __attribute__((ext_vector_type(8))) short short8;
typedef __attribute__((ext_vector_type(4))) float f32x4;
typedef __attribute__((ext_vector_type(4))) unsigned short us4;

#define GAS(p) ((const __attribute__((address_space(1))) void*)(p))
#define LAS(p) ((__attribute__((address_space(3))) void*)(p))

__device__ __forceinline__ unsigned short f2bf(float f) {
  union { float f; unsigned u; } v; v.f = f;
  return (unsigned short)((v.u + 0x7fffu + ((v.u >> 16) & 1u)) >> 16);
}

// ---------- fp32 -> bf16 convert (x4 vectorized) ----------
__global__ __launch_bounds__(256) void cvt_kernel(const float* __restrict__ in,
                                                  unsigned short* __restrict__ out, int n4) {
  int i = blockIdx.x * 256 + threadIdx.x;
  if (i >= n4) return;
  f32x4 v = ((const f32x4*)in)[i];
  us4 o;
#pragma unroll
  for (int j = 0; j < 4; ++j) o[j] = f2bf(v[j]);
  ((us4*)out)[i] = o;
}

// ---------- LayerNorm: one wave per row of 768, bf16 out ----------
__global__ __launch_bounds__(256) void ln_kernel(const float* __restrict__ x,
                                                 const float* __restrict__ g,
                                                 const float* __restrict__ b,
                                                 unsigned short* __restrict__ out) {
  const int wave = threadIdx.x >> 6, lane = threadIdx.x & 63;
  const int row = blockIdx.x * 4 + wave;
  const float* xr = x + (size_t)row * 768;
  f32x4 v[3];
  float s = 0.f, sq = 0.f;
#pragma unroll
  for (int c = 0; c < 3; ++c) {
    v[c] = *(const f32x4*)(xr + c * 256 + lane * 4);
#pragma unroll
    for (int j = 0; j < 4; ++j) { s += v[c][j]; sq += v[c][j] * v[c][j]; }
  }
#pragma unroll
  for (int off = 32; off > 0; off >>= 1) { s += __shfl_xor(s, off); sq += __shfl_xor(sq, off); }
  const float mu = s * (1.f / 768.f);
  const float var = sq * (1.f / 768.f) - mu * mu;
  const float rs = rsqrtf(var + 1e-5f);
  unsigned short* orow = out + (size_t)row * 768;
#pragma unroll
  for (int c = 0; c < 3; ++c) {
    f32x4 gg = *(const f32x4*)(g + c * 256 + lane * 4);
    f32x4 bb = *(const f32x4*)(b + c * 256 + lane * 4);
    us4 o;
#pragma unroll
    for (int j = 0; j < 4; ++j) o[j] = f2bf((v[c][j] - mu) * rs * gg[j] + bb[j]);
    *(us4*)(orow + c * 256 + lane * 4) = o;
  }
}

// ---------- GEMM: C[M,NN] = A[M,K](bf16) @ W[NN,K]^T(bf16) ----------
// 256x256 tile, 512 threads (8 waves, 2Mx4N), BK=32, FOUR LDS buffers.
// One barrier + one COUNTED vmcnt per K-tile; tile t+3 staged right after the
// tile-t barrier -> issue-to-use distance = 3 K-tiles (~3000 cyc), steady-state
// wait vmcnt(8) only drains the 3-tile-old loads (never vmcnt(0) mid-loop).
// K-loop unrolled x4 so buffer indices and LDS addresses are compile-time.
// r5-verified 0-conflict XOR swizzle (64B rows, chunk ^ (row>>1)&3, both-sides).
// EPI 0: qkv scatter -> q (prescaled by 0.125), k [B,H,N,64], vt [B,H,64,N]
// EPI 1: outF = acc + bias[col] + res[idx]   (fp32)
// EPI 2: outU = bf16(gelu_sigmoid(acc + bias[col]))
template <int EPI, int NN, int K>
__global__ __launch_bounds__(512, 2) void gemmP(
    const unsigned short* __restrict__ A, const unsigned short* __restrict__ W,
    float* __restrict__ outF, const float* __restrict__ bias, const float* __restrict__ res,
    unsigned short* __restrict__ outU,
    unsigned short* __restrict__ q, unsigned short* __restrict__ kk, unsigned short* __restrict__ vt) {
  __shared__ unsigned short As[4][8192];   // [buf][256 rows x 32 ushorts (64B)]
  __shared__ unsigned short Bs[4][8192];
  const int tid = threadIdx.x;
  const int wave = tid >> 6, lane = tid & 63;
  const int lr = lane & 15, lg = lane >> 4;
  const int wr = wave >> 2, wc = wave & 3;
  constexpr int GX = NN / 256;
  constexpr int NWG = GX * 64;             // M=16384 -> 64 row tiles; NWG % 8 == 0
  int id = blockIdx.y * GX + blockIdx.x;
  id = (id & 7) * (NWG / 8) + (id >> 3);   // bijective XCD swizzle
  const int row0 = (id / GX) * 256, col0 = (id % GX) * 256;
  f32x4 acc[8][4] = {};
  // staging: thread t -> row t>>2 (+128 for 2nd issue), LDS chunk t&3 (linear
  // dest); global chunk pre-swizzled ^((t>>3)&3) so LDS[row][c] = global c^((row>>1)&3)
  const int sc = ((tid & 3) ^ ((tid >> 3) & 3)) * 8;
  const unsigned short* ag = A + (size_t)(row0 + (tid >> 2)) * K + sc;
  const unsigned short* bg = W + (size_t)(col0 + (tid >> 2)) * K + sc;
  const int rsw = (lg ^ ((lr >> 1) & 3)) << 4;   // read-side byte XOR within 64B row
  const int KT = K / 32;                          // 24 or 96 (divisible by 4)

#define STG(buf, t_)                                                                           \
  {                                                                                            \
    const unsigned short* a0 = ag + (t_) * 32;                                                 \
    const unsigned short* b0 = bg + (t_) * 32;                                                 \
    __builtin_amdgcn_global_load_lds(GAS(a0), LAS(&As[buf][wave * 512]), 16, 0, 0);            \
    __builtin_amdgcn_global_load_lds(GAS(a0 + (size_t)128 * K), LAS(&As[buf][4096 + wave * 512]), 16, 0, 0); \
    __builtin_amdgcn_global_load_lds(GAS(b0), LAS(&Bs[buf][wave * 512]), 16, 0, 0);            \
    __builtin_amdgcn_global_load_lds(GAS(b0 + (size_t)128 * K), LAS(&Bs[buf][4096 + wave * 512]), 16, 0, 0); \
  }

#define TILE(buf, t_)                                                                          \
  {                                                                                            \
    if ((t_) < KT - 2)       { asm volatile("s_waitcnt vmcnt(8)" ::: "memory"); }              \
    else if ((t_) == KT - 2) { asm volatile("s_waitcnt vmcnt(4)" ::: "memory"); }              \
    else                     { asm volatile("s_waitcnt vmcnt(0)" ::: "memory"); }              \
    __builtin_amdgcn_s_barrier();                                                              \
    if ((t_) + 3 < KT) STG(((buf) + 3) & 3, (t_) + 3);                                         \
    const char* Ab = (const char*)As + (buf) * 16384;                                          \
    const char* Bb = (const char*)Bs + (buf) * 16384;                                          \
    short8 af[8], bfv[4];                                                                      \
    _Pragma("unroll")                                                                          \
    for (int m = 0; m < 8; ++m) {                                                              \
      const int arow = wr * 128 + m * 16 + lr;                                                 \
      af[m] = *(const short8*)(Ab + arow * 64 + rsw);                                          \
    }                                                                                          \
    _Pragma("unroll")                                                                          \
    for (int n = 0; n < 4; ++n) {                                                              \
      const int brow = wc * 64 + n * 16 + lr;                                                  \
      bfv[n] = *(const short8*)(Bb + brow * 64 + rsw);                                         \
    }                                                                                          \
    __builtin_amdgcn_s_setprio(1);                                                             \
    _Pragma("unroll")                                                                          \
    for (int m = 0; m < 8; ++m)                                                                \
      _Pragma("unroll")                                                                        \
      for (int n = 0; n < 4; ++n)                                                              \
        acc[m][n] = __builtin_amdgcn_mfma_f32_16x16x32_bf16(af[m], bfv[n], acc[m][n], 0, 0, 0);\
    __builtin_amdgcn_s_setprio(0);                                                             \
  }

  // prologue: stage tiles 0,1,2 (KT >= 4 always)
  STG(0, 0);
  STG(1, 1);
  STG(2, 2);
  for (int tt = 0; tt < KT; tt += 4) {
    TILE(0, tt);
    TILE(1, tt + 1);
    TILE(2, tt + 2);
    TILE(3, tt + 3);
  }
#undef TILE
#undef STG

  if (EPI == 0) {
    // segment is block-uniform: col tiles are 256-wide, segment boundaries at 768/1536
    const int s = (col0 >= 1536) ? 2 : (col0 >= 768 ? 1 : 0);
    const int base = col0 + wc * 64 - s * 768;   // multiple of 64
    const int hh = base >> 6;
#pragma unroll
    for (int m = 0; m < 8; ++m)
#pragma unroll
      for (int n = 0; n < 4; ++n) {
        const int d = n * 16 + lr;
#pragma unroll
        for (int r = 0; r < 4; ++r) {
          const int grow = row0 + wr * 128 + m * 16 + lg * 4 + r;
          const int bt = grow >> 10, nt = grow & 1023;
          const size_t bh = (size_t)(bt * 12 + hh);
          const float val = acc[m][n][r];
          if (s == 0)      q[(bh * 1024 + nt) * 64 + d] = f2bf(val * 0.125f);
          else if (s == 1) kk[(bh * 1024 + nt) * 64 + d] = f2bf(val);
          else             vt[(bh * 64 + d) * 1024 + nt] = f2bf(val);
        }
      }
  } else if (EPI == 1) {
#pragma unroll
    for (int n = 0; n < 4; ++n) {
      const int gcol = col0 + wc * 64 + n * 16 + lr;
      const float bn = bias[gcol];
#pragma unroll
      for (int m = 0; m < 8; ++m)
#pragma unroll
        for (int r = 0; r < 4; ++r) {
          const int grow = row0 + wr * 128 + m * 16 + lg * 4 + r;
          const size_t idx = (size_t)grow * NN + gcol;
          outF[idx] = acc[m][n][r] + bn + res[idx];
        }
    }
  } else {
#pragma unroll
    for (int n = 0; n < 4; ++n) {
      const int gcol = col0 + wc * 64 + n * 16 + lr;
      const float bn = bias[gcol];
#pragma unroll
      for (int m = 0; m < 8; ++m)
#pragma unroll
        for (int r = 0; r < 4; ++r) {
          const int grow = row0 + wr * 128 + m * 16 + lg * 4 + r;
          const size_t idx = (size_t)grow * NN + gcol;
          const float t = acc[m][n][r] + bn;
          // gelu via sigmoid form: t * sigmoid(1.5957691*t + 0.0713548*t^3)
          const float u = t * (1.59576912f + t * t * 0.07135481f);
          const float eu = __expf(-u);
          outU[idx] = f2bf(t / (1.f + eu));
        }
    }
  }
}

// ---------- Flash attention, swapped-operand (S^T / O^T), in-register softmax ----------
// block = (qtile of 128, head, batch), 4 waves x 32 q-rows; KV tiles of 64,
// depth-2 pipeline with counted vmcnt + raw barriers.
__global__ __launch_bounds__(256) void attn_kernel(
    const unsigned short* __restrict__ Q, const unsigned short* __restrict__ K,
    const unsigned short* __restrict__ V, unsigned short* __restrict__ O) {
  __shared__ unsigned short Ks[2][64 * 64];  // [kv][d], chunk-swizzled rows
  __shared__ unsigned short Vs[2][64 * 64];  // [d][kv], chunk-swizzled rows
  const int tid = threadIdx.x, wave = tid >> 6, lane = tid & 63;
  const int lr = lane & 15, lg = lane >> 4;
  const int qt = blockIdx.x, hh = blockIdx.y, bb = blockIdx.z;
  const size_t bh = (size_t)bb * 12 + hh;
  const unsigned short* Qg = Q + bh * 1024 * 64;
  const unsigned short* Kg = K + bh * 1024 * 64;
  const unsigned short* Vg = V + bh * 64 * 1024;
  const int q0 = qt * 128 + wave * 32;
  short8 aq[2][2];  // [nq][kb]
#pragma unroll
  for (int nq = 0; nq < 2; ++nq)
#pragma unroll
    for (int kb = 0; kb < 2; ++kb)
      aq[nq][kb] = *(const short8*)(Qg + (size_t)(q0 + nq * 16 + lr) * 64 + kb * 32 + lg * 8);
  float m_run[2] = {-1e30f, -1e30f}, l_run[2] = {0.f, 0.f};
  f32x4 oacc[4][2] = {};  // [mb over d][nq], O^T layout: col=q(lr), row=d
  const int srow = tid >> 3;                                      // staging row 0..31
  const int sswz = (((tid & 7) * 16) ^ ((srow & 7) << 4)) >> 1;   // pre-swizzled src (ushort)
  const int srcLo = (lane & 15) | ((lane & 16) << 1);             // lr + 32*(lg&1)
  const int srcHi = srcLo + 16;
  const bool hiSel = lg >= 2;
#define ATTN_STAGE(buf, t_)                                                                      \
  {                                                                                              \
    const int kv_ = (t_) * 64;                                                                   \
    _Pragma("unroll")                                                                            \
    for (int is = 0; is < 2; ++is) {                                                             \
      __builtin_amdgcn_global_load_lds(GAS(Kg + (size_t)(kv_ + is * 32 + srow) * 64 + sswz),     \
                                       LAS(&Ks[buf][is * 2048 + wave * 512]), 16, 0, 0);         \
      __builtin_amdgcn_global_load_lds(GAS(Vg + (size_t)(is * 32 + srow) * 1024 + kv_ + sswz),   \
                                       LAS(&Vs[buf][is * 2048 + wave * 512]), 16, 0, 0);         \
    }                                                                                            \
  }
  ATTN_STAGE(0, 0);
  ATTN_STAGE(1, 1);
  for (int t = 0; t < 16; ++t) {
    const int cur = t & 1;
    if (t < 15) asm volatile("s_waitcnt vmcnt(4)" ::: "memory");
    else        asm volatile("s_waitcnt vmcnt(0)" ::: "memory");
    __builtin_amdgcn_s_barrier();        // tile t ready in buf[cur]
    __builtin_amdgcn_sched_barrier(0);
    f32x4 sacc[4][2] = {};  // [mk][nq]; lane: col q = nq*16+lr, rows kv = mk*16+lg*4+r
#pragma unroll
    for (int kb = 0; kb < 2; ++kb) {
      short8 kf[4];
#pragma unroll
      for (int mk = 0; mk < 4; ++mk) {
        const int row = mk * 16 + lr;
        const int boff = row * 128 + ((kb * 64 + lg * 16) ^ ((row & 7) << 4));
        kf[mk] = *(const short8*)((const char*)&Ks[cur][0] + boff);
      }
#pragma unroll
      for (int mk = 0; mk < 4; ++mk)
#pragma unroll
        for (int nq = 0; nq < 2; ++nq)
          sacc[mk][nq] = __builtin_amdgcn_mfma_f32_16x16x32_bf16(kf[mk], aq[nq][kb], sacc[mk][nq], 0, 0, 0);
    }
    unsigned pk[4][2][2];
#pragma unroll
    for (int nq = 0; nq < 2; ++nq) {
      float mx = sacc[0][nq][0];
#pragma unroll
      for (int mk = 0; mk < 4; ++mk)
#pragma unroll
        for (int r = 0; r < 4; ++r) mx = fmaxf(mx, sacc[mk][nq][r]);
      mx = fmaxf(mx, __shfl_xor(mx, 16));
      mx = fmaxf(mx, __shfl_xor(mx, 32));
      const float mnew = fmaxf(m_run[nq], mx);
      const float alpha = __expf(m_run[nq] - mnew);
      float ssum = 0.f;
#pragma unroll
      for (int mk = 0; mk < 4; ++mk)
#pragma unroll
        for (int r = 0; r < 4; ++r) {
          const float p = __expf(sacc[mk][nq][r] - mnew);
          sacc[mk][nq][r] = p;
          ssum += p;
        }
      ssum += __shfl_xor(ssum, 16);
      ssum += __shfl_xor(ssum, 32);
      l_run[nq] = alpha * l_run[nq] + ssum;
      m_run[nq] = mnew;
#pragma unroll
      for (int mb = 0; mb < 4; ++mb)
#pragma unroll
        for (int r = 0; r < 4; ++r) oacc[mb][nq][r] *= alpha;
#pragma unroll
      for (int mk = 0; mk < 4; ++mk) {
        asm("v_cvt_pk_bf16_f32 %0, %1, %2" : "=v"(pk[mk][nq][0]) : "v"(sacc[mk][nq][0]), "v"(sacc[mk][nq][1]));
        asm("v_cvt_pk_bf16_f32 %0, %1, %2" : "=v"(pk[mk][nq][1]) : "v"(sacc[mk][nq][2]), "v"(sacc[mk][nq][3]));
      }
    }
#pragma unroll
    for (int kb = 0; kb < 2; ++kb) {
      short8 vf[4];
#pragma unroll
      for (int mb = 0; mb < 4; ++mb) {
        const int row = mb * 16 + lr;
        const int boff = row * 128 + ((kb * 64 + lg * 16) ^ ((row & 7) << 4));
        vf[mb] = *(const short8*)((const char*)&Vs[cur][0] + boff);
      }
#pragma unroll
      for (int nq = 0; nq < 2; ++nq) {
        unsigned a0 = (unsigned)__shfl((int)pk[2 * kb][nq][0], srcLo);
        unsigned b0 = (unsigned)__shfl((int)pk[2 * kb + 1][nq][0], srcLo);
        unsigned a1 = (unsigned)__shfl((int)pk[2 * kb][nq][1], srcLo);
        unsigned b1 = (unsigned)__shfl((int)pk[2 * kb + 1][nq][1], srcLo);
        unsigned a2 = (unsigned)__shfl((int)pk[2 * kb][nq][0], srcHi);
        unsigned b2 = (unsigned)__shfl((int)pk[2 * kb + 1][nq][0], srcHi);
        unsigned a3 = (unsigned)__shfl((int)pk[2 * kb][nq][1], srcHi);
        unsigned b3 = (unsigned)__shfl((int)pk[2 * kb + 1][nq][1], srcHi);
        union { unsigned u[4]; short8 s; } cvt;
        cvt.u[0] = hiSel ? b0 : a0;
        cvt.u[1] = hiSel ? b1 : a1;
        cvt.u[2] = hiSel ? b2 : a2;
        cvt.u[3] = hiSel ? b3 : a3;
        const short8 pb = cvt.s;
#pragma unroll
        for (int mb = 0; mb < 4; ++mb)
          oacc[mb][nq] = __builtin_amdgcn_mfma_f32_16x16x32_bf16(vf[mb], pb, oacc[mb][nq], 0, 0, 0);
      }
    }
    asm volatile("s_waitcnt lgkmcnt(0)" ::: "memory");
    __builtin_amdgcn_sched_barrier(0);
    __builtin_amdgcn_s_barrier();        // all waves done reading buf[cur]
    if (t + 2 < 16) ATTN_STAGE(cur, t + 2);
  }
#undef ATTN_STAGE
#pragma unroll
  for (int nq = 0; nq < 2; ++nq) {
    const float linv = 1.f / l_run[nq];
    const size_t tok = (size_t)(bb << 10) + q0 + nq * 16 + lr;
#pragma unroll
    for (int mb = 0; mb < 4; ++mb) {
      us4 o;
#pragma unroll
      for (int r = 0; r < 4; ++r) o[r] = f2bf(oacc[mb][nq][r] * linv);
      *(us4*)(O + tok * 768 + hh * 64 + mb * 16 + lg * 4) = o;
    }
  }
}

extern "C" void kernel_launch(void* const* d_in, const int* in_sizes, int n_in,
                              void* d_out, int out_size, void* d_ws, size_t ws_size,
                              hipStream_t stream) {
  const float* x      = (const float*)d_in[0];
  const float* ln1_g  = (const float*)d_in[1];
  const float* ln1_b  = (const float*)d_in[2];
  const float* qkv_w  = (const float*)d_in[3];
  const float* proj_w = (const float*)d_in[4];
  const float* proj_b = (const float*)d_in[5];
  const float* ln2_g  = (const float*)d_in[6];
  const float* ln2_b  = (const float*)d_in[7];
  const float* fc1_w  = (const float*)d_in[8];
  const float* fc1_b  = (const float*)d_in[9];
  const float* fc2_w  = (const float*)d_in[10];
  const float* fc2_b  = (const float*)d_in[11];
  float* out = (float*)d_out;
  char* ws = (char*)d_ws;

  unsigned short* wqkv = (unsigned short*)(ws + 0);
  unsigned short* wproj = (unsigned short*)(ws + 3538944);
  unsigned short* wfc1 = (unsigned short*)(ws + 4718592);
  unsigned short* wfc2 = (unsigned short*)(ws + 9437184);
  unsigned short* hbuf = (unsigned short*)(ws + 14155776);          // 16384x768 bf16
  char* big = ws + 39321600;                                        // 96 MB region
  unsigned short* qb  = (unsigned short*)(big);
  unsigned short* kb  = (unsigned short*)(big + 25165824);
  unsigned short* vtb = (unsigned short*)(big + 50331648);
  unsigned short* ob  = (unsigned short*)(big + 75497472);
  unsigned short* hid = (unsigned short*)(big);                     // reuses q/k/vt/o after attn+proj

  // weights -> bf16
  cvt_kernel<<<1728, 256, 0, stream>>>(qkv_w, wqkv, 442368);
  cvt_kernel<<<576, 256, 0, stream>>>(proj_w, wproj, 147456);
  cvt_kernel<<<2304, 256, 0, stream>>>(fc1_w, wfc1, 589824);
  cvt_kernel<<<2304, 256, 0, stream>>>(fc2_w, wfc2, 589824);

  // LN1
  ln_kernel<<<4096, 256, 0, stream>>>(x, ln1_g, ln1_b, hbuf);
  // QKV
  gemmP<0, 2304, 768><<<dim3(9, 64), 512, 0, stream>>>(
      hbuf, wqkv, nullptr, nullptr, nullptr, nullptr, qb, kb, vtb);
  // attention
  attn_kernel<<<dim3(8, 12, 16), 256, 0, stream>>>(qb, kb, vtb, ob);
  // proj + residual -> x1 (in d_out)
  gemmP<1, 768, 768><<<dim3(3, 64), 512, 0, stream>>>(
      ob, wproj, out, proj_b, x, nullptr, nullptr, nullptr, nullptr);
  // LN2
  ln_kernel<<<4096, 256, 0, stream>>>(out, ln2_g, ln2_b, hbuf);
  // FC1 + gelu
  gemmP<2, 3072, 768><<<dim3(12, 64), 512, 0, stream>>>(
      hbuf, wfc1, nullptr, fc1_b, nullptr, hid, nullptr, nullptr, nullptr);
  // FC2 + residual -> out
  gemmP<1, 768, 3072><<<dim3(3, 64), 512, 0, stream>>>(
      hid, wfc2, out, fc2_b, out, nullptr, nullptr, nullptr, nullptr);
}

// Round 10
// 517.726 us; speedup vs baseline: 1.1149x; 1.0766x over previous
//
#include <hip/hip_runtime.h>
#include <cstdint>
#include <cstddef>

typedef __attribute__((ext_vector_type(8))) short short8;
typedef __attribute__((ext_vector_type(4))) float f32x4;
typedef __attribute__((ext_vector_type(4))) unsigned short us4;

#define GAS(p) ((const __attribute__((address_space(1))) void*)(p))
#define LAS(p) ((__attribute__((address_space(3))) void*)(p))

__device__ __forceinline__ unsigned short f2bf(float f) {
  union { float f; unsigned u; } v; v.f = f;
  return (unsigned short)((v.u + 0x7fffu + ((v.u >> 16) & 1u)) >> 16);
}

// ---------- fp32 -> bf16 convert (x4 vectorized) ----------
__global__ __launch_bounds__(256) void cvt_kernel(const float* __restrict__ in,
                                                  unsigned short* __restrict__ out, int n4) {
  int i = blockIdx.x * 256 + threadIdx.x;
  if (i >= n4) return;
  f32x4 v = ((const f32x4*)in)[i];
  us4 o;
#pragma unroll
  for (int j = 0; j < 4; ++j) o[j] = f2bf(v[j]);
  ((us4*)out)[i] = o;
}

// ---------- LayerNorm: one wave per row of 768, bf16 out ----------
__global__ __launch_bounds__(256) void ln_kernel(const float* __restrict__ x,
                                                 const float* __restrict__ g,
                                                 const float* __restrict__ b,
                                                 unsigned short* __restrict__ out) {
  const int wave = threadIdx.x >> 6, lane = threadIdx.x & 63;
  const int row = blockIdx.x * 4 + wave;
  const float* xr = x + (size_t)row * 768;
  f32x4 v[3];
  float s = 0.f, sq = 0.f;
#pragma unroll
  for (int c = 0; c < 3; ++c) {
    v[c] = *(const f32x4*)(xr + c * 256 + lane * 4);
#pragma unroll
    for (int j = 0; j < 4; ++j) { s += v[c][j]; sq += v[c][j] * v[c][j]; }
  }
#pragma unroll
  for (int off = 32; off > 0; off >>= 1) { s += __shfl_xor(s, off); sq += __shfl_xor(sq, off); }
  const float mu = s * (1.f / 768.f);
  const float var = sq * (1.f / 768.f) - mu * mu;
  const float rs = rsqrtf(var + 1e-5f);
  unsigned short* orow = out + (size_t)row * 768;
#pragma unroll
  for (int c = 0; c < 3; ++c) {
    f32x4 gg = *(const f32x4*)(g + c * 256 + lane * 4);
    f32x4 bb = *(const f32x4*)(b + c * 256 + lane * 4);
    us4 o;
#pragma unroll
    for (int j = 0; j < 4; ++j) o[j] = f2bf((v[c][j] - mu) * rs * gg[j] + bb[j]);
    *(us4*)(orow + c * 256 + lane * 4) = o;
  }
}

// ---------- GEMM: C[M,NN] = A[M,K](bf16) @ W[NN,K]^T(bf16) ----------
// 8-phase schedule, RACE-FIXED: vmcnt waits moved to END of staging phases
// (after MFMA, before the closing barrier) so the barrier publishes all
// waves' slices before any consuming ds_read.
// 256x256 tile, 8 waves (2Mx4N), BK=64, two K-tile LDS buffers (128 KB).
// Phase = {4|8 ds_read_b128 ; one burst stage ; s_barrier ; lgkmcnt(0)+
// sched_barrier ; setprio(1) ; 16 MFMA ; setprio(0) ; [ENDWAIT] ; s_barrier}.
// Per-wave in-flight: prologue 12 -> vmcnt(4)+barrier; steady: PH4-end
// vmcnt(4) (publishes d1), PH8-end vmcnt(4) (publishes next d0); tail PH4-end
// vmcnt(0). Slot reuse: A[d0] read ph1-4 -> restaged ph5; B[d0] ph1,3 -> ph4;
// B[d1] ph5,7 -> ph8; A[d1] ph5-8 -> ph1 next. r7-verified 0-conflict swizzle.
// EPI 0: qkv scatter -> q (prescaled 0.125), k [B,H,N,64], vt [B,H,64,N]
// EPI 1: outF = acc + bias[col] + res[idx]   (fp32)
// EPI 2: outU = bf16(gelu_sigmoid(acc + bias[col]))
template <int EPI, int NN, int K>
__global__ __launch_bounds__(512, 1) void gemm8(
    const unsigned short* __restrict__ A, const unsigned short* __restrict__ W,
    float* __restrict__ outF, const float* __restrict__ bias, const float* __restrict__ res,
    unsigned short* __restrict__ outU,
    unsigned short* __restrict__ q, unsigned short* __restrict__ kk, unsigned short* __restrict__ vt) {
  __shared__ unsigned short As[2][16384];   // [d][256 rows x 64 ushorts (128B)]
  __shared__ unsigned short Bs[2][16384];
  const int tid = threadIdx.x;
  const int wave = tid >> 6, lane = tid & 63;
  const int lr = lane & 15, lg = lane >> 4;
  const int wr = wave >> 2, wc = wave & 3;
  constexpr int GX = NN / 256;
  constexpr int NWG = GX * 64;              // M=16384 -> 64 row tiles; NWG % 8 == 0
  int id = blockIdx.y * GX + blockIdx.x;
  id = (id & 7) * (NWG / 8) + (id >> 3);    // bijective XCD swizzle
  const int row0 = (id / GX) * 256, col0 = (id % GX) * 256;
  f32x4 acc[8][4] = {};
  short8 bq[4];
  // staging: thread t -> row (t>>3) within a 64-row issue, chunk t&7 (linear
  // LDS dest); global chunk pre-swizzled ^((t>>3)&7) so LDS[row][c] holds
  // global chunk c ^ (row&7)  [r7: 0 bank conflicts, refchecked]
  const int sc8 = ((tid & 7) ^ ((tid >> 3) & 7)) * 8;
  const unsigned short* ag = A + (size_t)(row0 + (tid >> 3)) * K + sc8;
  const unsigned short* bg = W + (size_t)(col0 + (tid >> 3)) * K + sc8;
  constexpr int KT = K / 64;                // 12 or 48 (even)
  constexpr int NI = KT / 2;

#define SG_A(d, t_)                                                                            \
  {                                                                                            \
    const unsigned short* p_ = ag + (t_) * 64;                                                 \
    _Pragma("unroll")                                                                          \
    for (int i_ = 0; i_ < 4; ++i_)                                                             \
      __builtin_amdgcn_global_load_lds(GAS(p_ + (size_t)(i_ * 64) * K),                        \
                                       LAS(&As[d][i_ * 4096 + wave * 512]), 16, 0, 0);         \
  }
#define SG_B(d, t_)                                                                            \
  {                                                                                            \
    const unsigned short* p_ = bg + (t_) * 64;                                                 \
    _Pragma("unroll")                                                                          \
    for (int i_ = 0; i_ < 4; ++i_)                                                             \
      __builtin_amdgcn_global_load_lds(GAS(p_ + (size_t)(i_ * 64) * K),                        \
                                       LAS(&Bs[d][i_ * 4096 + wave * 512]), 16, 0, 0);         \
  }

#define PH(d, kb, mh, STAGEC, ENDWAIT)                                                         \
  {                                                                                            \
    short8 af[4];                                                                              \
    _Pragma("unroll")                                                                          \
    for (int mm = 0; mm < 4; ++mm) {                                                           \
      const int row = wr * 128 + ((mh) * 4 + mm) * 16 + lr;                                    \
      af[mm] = *(const short8*)((const char*)&As[d][0] + row * 128 +                           \
                                (((kb) * 64 + lg * 16) ^ ((row & 7) << 4)));                   \
    }                                                                                          \
    if ((mh) == 0) {                                                                           \
      _Pragma("unroll")                                                                        \
      for (int nn = 0; nn < 4; ++nn) {                                                         \
        const int row = wc * 64 + nn * 16 + lr;                                                \
        bq[nn] = *(const short8*)((const char*)&Bs[d][0] + row * 128 +                         \
                                  (((kb) * 64 + lg * 16) ^ ((row & 7) << 4)));                 \
      }                                                                                        \
    }                                                                                          \
    STAGEC;                                                                                    \
    __builtin_amdgcn_s_barrier();                                                              \
    asm volatile("s_waitcnt lgkmcnt(0)" ::: "memory");                                         \
    __builtin_amdgcn_sched_barrier(0);                                                         \
    __builtin_amdgcn_s_setprio(1);                                                             \
    _Pragma("unroll")                                                                          \
    for (int mm = 0; mm < 4; ++mm)                                                             \
      _Pragma("unroll")                                                                        \
      for (int nn = 0; nn < 4; ++nn)                                                           \
        acc[(mh) * 4 + mm][nn] = __builtin_amdgcn_mfma_f32_16x16x32_bf16(                      \
            af[mm], bq[nn], acc[(mh) * 4 + mm][nn], 0, 0, 0);                                  \
    __builtin_amdgcn_s_setprio(0);                                                             \
    ENDWAIT;                                                                                   \
    __builtin_amdgcn_s_barrier();                                                              \
  }

#define VM4 asm volatile("s_waitcnt vmcnt(4)" ::: "memory")
#define VM0 asm volatile("s_waitcnt vmcnt(0)" ::: "memory")
#define NOOP

  // prologue: tile0 -> d0 (A+B), tile1's B -> d1; publish d0 before PH1 reads
  SG_A(0, 0); SG_B(0, 0); SG_B(1, 1);
  VM4;                                      // drain A0,B0 (leave B1 in flight)
  __builtin_amdgcn_s_barrier();             // publish d0 across waves
  for (int j = 0; j < NI - 1; ++j) {
    PH(0, 0, 0, SG_A(1, 2 * j + 1), NOOP);
    PH(0, 0, 1, NOOP, NOOP);
    PH(0, 1, 0, NOOP, NOOP);
    PH(0, 1, 1, SG_B(0, 2 * j + 2), VM4);   // publish d1 (A1,B1 drained)
    PH(1, 0, 0, SG_A(0, 2 * j + 2), NOOP);
    PH(1, 0, 1, NOOP, NOOP);
    PH(1, 1, 0, NOOP, NOOP);
    PH(1, 1, 1, SG_B(1, 2 * j + 3), VM4);   // publish next d0
  }
  // peeled final iteration
  PH(0, 0, 0, SG_A(1, KT - 1), NOOP);
  PH(0, 0, 1, NOOP, NOOP);
  PH(0, 1, 0, NOOP, NOOP);
  PH(0, 1, 1, NOOP, VM0);                   // publish d1 (drain everything)
  PH(1, 0, 0, NOOP, NOOP);
  PH(1, 0, 1, NOOP, NOOP);
  PH(1, 1, 0, NOOP, NOOP);
  PH(1, 1, 1, NOOP, NOOP);
#undef PH
#undef SG_A
#undef SG_B
#undef VM4
#undef VM0
#undef NOOP

  if (EPI == 0) {
    // segment is block-uniform: col tiles 256-wide, boundaries at 768/1536
    const int s = (col0 >= 1536) ? 2 : (col0 >= 768 ? 1 : 0);
    const int hh = (col0 + wc * 64 - s * 768) >> 6;
#pragma unroll
    for (int m = 0; m < 8; ++m)
#pragma unroll
      for (int n = 0; n < 4; ++n) {
        const int d = n * 16 + lr;
        const int nt0 = (row0 + wr * 128 + m * 16 + lg * 4) & 1023;
        const int bt = (row0 + wr * 128 + m * 16 + lg * 4) >> 10;
        const size_t bh = (size_t)(bt * 12 + hh);
        if (s == 2) {
          us4 o;
#pragma unroll
          for (int r = 0; r < 4; ++r) o[r] = f2bf(acc[m][n][r]);
          *(us4*)(vt + (bh * 64 + d) * 1024 + nt0) = o;
        } else {
#pragma unroll
          for (int r = 0; r < 4; ++r) {
            const float val = acc[m][n][r];
            if (s == 0) q[(bh * 1024 + nt0 + r) * 64 + d] = f2bf(val * 0.125f);
            else        kk[(bh * 1024 + nt0 + r) * 64 + d] = f2bf(val);
          }
        }
      }
  } else if (EPI == 1) {
#pragma unroll
    for (int m = 0; m < 8; ++m)
#pragma unroll
      for (int n = 0; n < 4; ++n) {
        const int gcol = col0 + wc * 64 + n * 16 + lr;
        const float bn = bias[gcol];
#pragma unroll
        for (int r = 0; r < 4; ++r) {
          const int grow = row0 + wr * 128 + m * 16 + lg * 4 + r;
          const size_t idx = (size_t)grow * NN + gcol;
          outF[idx] = acc[m][n][r] + bn + res[idx];
        }
      }
  } else {
#pragma unroll
    for (int m = 0; m < 8; ++m)
#pragma unroll
      for (int n = 0; n < 4; ++n) {
        const int gcol = col0 + wc * 64 + n * 16 + lr;
        const float bn = bias[gcol];
#pragma unroll
        for (int r = 0; r < 4; ++r) {
          const int grow = row0 + wr * 128 + m * 16 + lg * 4 + r;
          const size_t idx = (size_t)grow * NN + gcol;
          const float t = acc[m][n][r] + bn;
          const float u = t * (1.59576912f + t * t * 0.07135481f);
          const float eu = __expf(-u);
          outU[idx] = f2bf(t / (1.f + eu));
        }
      }
  }
}

// ---------- Flash attention, swapped-operand (S^T / O^T), in-register softmax ----------
__global__ __launch_bounds__(256) void attn_kernel(
    const unsigned short* __restrict__ Q, const unsigned short* __restrict__ K,
    const unsigned short* __restrict__ V, unsigned short* __restrict__ O) {
  __shared__ unsigned short Ks[2][64 * 64];  // [kv][d], chunk-swizzled rows
  __shared__ unsigned short Vs[2][64 * 64];  // [d][kv], chunk-swizzled rows
  const int tid = threadIdx.x, wave = tid >> 6, lane = tid & 63;
  const int lr = lane & 15, lg = lane >> 4;
  const int qt = blockIdx.x, hh = blockIdx.y, bb = blockIdx.z;
  const size_t bh = (size_t)bb * 12 + hh;
  const unsigned short* Qg = Q + bh * 1024 * 64;
  const unsigned short* Kg = K + bh * 1024 * 64;
  const unsigned short* Vg = V + bh * 64 * 1024;
  const int q0 = qt * 128 + wave * 32;
  short8 aq[2][2];  // [nq][kb]
#pragma unroll
  for (int nq = 0; nq < 2; ++nq)
#pragma unroll
    for (int kb = 0; kb < 2; ++kb)
      aq[nq][kb] = *(const short8*)(Qg + (size_t)(q0 + nq * 16 + lr) * 64 + kb * 32 + lg * 8);
  float m_run[2] = {-1e30f, -1e30f}, l_run[2] = {0.f, 0.f};
  f32x4 oacc[4][2] = {};  // [mb over d][nq], O^T layout: col=q(lr), row=d
  const int srow = tid >> 3;
  const int sswz = (((tid & 7) * 16) ^ ((srow & 7) << 4)) >> 1;
  const int srcLo = (lane & 15) | ((lane & 16) << 1);
  const int srcHi = srcLo + 16;
  const bool hiSel = lg >= 2;
#define ATTN_STAGE(buf, t_)                                                                      \
  {                                                                                              \
    const int kv_ = (t_) * 64;                                                                   \
    _Pragma("unroll")                                                                            \
    for (int is = 0; is < 2; ++is) {                                                             \
      __builtin_amdgcn_global_load_lds(GAS(Kg + (size_t)(kv_ + is * 32 + srow) * 64 + sswz),     \
                                       LAS(&Ks[buf][is * 2048 + wave * 512]), 16, 0, 0);         \
      __builtin_amdgcn_global_load_lds(GAS(Vg + (size_t)(is * 32 + srow) * 1024 + kv_ + sswz),   \
                                       LAS(&Vs[buf][is * 2048 + wave * 512]), 16, 0, 0);         \
    }                                                                                            \
  }
  ATTN_STAGE(0, 0);
  ATTN_STAGE(1, 1);
  for (int t = 0; t < 16; ++t) {
    const int cur = t & 1;
    if (t < 15) asm volatile("s_waitcnt vmcnt(4)" ::: "memory");
    else        asm volatile("s_waitcnt vmcnt(0)" ::: "memory");
    __builtin_amdgcn_s_barrier();
    __builtin_amdgcn_sched_barrier(0);
    f32x4 sacc[4][2] = {};
#pragma unroll
    for (int kb = 0; kb < 2; ++kb) {
      short8 kf[4];
#pragma unroll
      for (int mk = 0; mk < 4; ++mk) {
        const int row = mk * 16 + lr;
        const int boff = row * 128 + ((kb * 64 + lg * 16) ^ ((row & 7) << 4));
        kf[mk] = *(const short8*)((const char*)&Ks[cur][0] + boff);
      }
#pragma unroll
      for (int mk = 0; mk < 4; ++mk)
#pragma unroll
        for (int nq = 0; nq < 2; ++nq)
          sacc[mk][nq] = __builtin_amdgcn_mfma_f32_16x16x32_bf16(kf[mk], aq[nq][kb], sacc[mk][nq], 0, 0, 0);
    }
    unsigned pk[4][2][2];
#pragma unroll
    for (int nq = 0; nq < 2; ++nq) {
      float mx = sacc[0][nq][0];
#pragma unroll
      for (int mk = 0; mk < 4; ++mk)
#pragma unroll
        for (int r = 0; r < 4; ++r) mx = fmaxf(mx, sacc[mk][nq][r]);
      mx = fmaxf(mx, __shfl_xor(mx, 16));
      mx = fmaxf(mx, __shfl_xor(mx, 32));
      const float mnew = fmaxf(m_run[nq], mx);
      const float alpha = __expf(m_run[nq] - mnew);
      float ssum = 0.f;
#pragma unroll
      for (int mk = 0; mk < 4; ++mk)
#pragma unroll
        for (int r = 0; r < 4; ++r) {
          const float p = __expf(sacc[mk][nq][r] - mnew);
          sacc[mk][nq][r] = p;
          ssum += p;
        }
      ssum += __shfl_xor(ssum, 16);
      ssum += __shfl_xor(ssum, 32);
      l_run[nq] = alpha * l_run[nq] + ssum;
      m_run[nq] = mnew;
#pragma unroll
      for (int mb = 0; mb < 4; ++mb)
#pragma unroll
        for (int r = 0; r < 4; ++r) oacc[mb][nq][r] *= alpha;
#pragma unroll
      for (int mk = 0; mk < 4; ++mk) {
        asm("v_cvt_pk_bf16_f32 %0, %1, %2" : "=v"(pk[mk][nq][0]) : "v"(sacc[mk][nq][0]), "v"(sacc[mk][nq][1]));
        asm("v_cvt_pk_bf16_f32 %0, %1, %2" : "=v"(pk[mk][nq][1]) : "v"(sacc[mk][nq][2]), "v"(sacc[mk][nq][3]));
      }
    }
#pragma unroll
    for (int kb = 0; kb < 2; ++kb) {
      short8 vf[4];
#pragma unroll
      for (int mb = 0; mb < 4; ++mb) {
        const int row = mb * 16 + lr;
        const int boff = row * 128 + ((kb * 64 + lg * 16) ^ ((row & 7) << 4));
        vf[mb] = *(const short8*)((const char*)&Vs[cur][0] + boff);
      }
#pragma unroll
      for (int nq = 0; nq < 2; ++nq) {
        unsigned a0 = (unsigned)__shfl((int)pk[2 * kb][nq][0], srcLo);
        unsigned b0 = (unsigned)__shfl((int)pk[2 * kb + 1][nq][0], srcLo);
        unsigned a1 = (unsigned)__shfl((int)pk[2 * kb][nq][1], srcLo);
        unsigned b1 = (unsigned)__shfl((int)pk[2 * kb + 1][nq][1], srcLo);
        unsigned a2 = (unsigned)__shfl((int)pk[2 * kb][nq][0], srcHi);
        unsigned b2 = (unsigned)__shfl((int)pk[2 * kb + 1][nq][0], srcHi);
        unsigned a3 = (unsigned)__shfl((int)pk[2 * kb][nq][1], srcHi);
        unsigned b3 = (unsigned)__shfl((int)pk[2 * kb + 1][nq][1], srcHi);
        union { unsigned u[4]; short8 s; } cvt;
        cvt.u[0] = hiSel ? b0 : a0;
        cvt.u[1] = hiSel ? b1 : a1;
        cvt.u[2] = hiSel ? b2 : a2;
        cvt.u[3] = hiSel ? b3 : a3;
        const short8 pb = cvt.s;
#pragma unroll
        for (int mb = 0; mb < 4; ++mb)
          oacc[mb][nq] = __builtin_amdgcn_mfma_f32_16x16x32_bf16(vf[mb], pb, oacc[mb][nq], 0, 0, 0);
      }
    }
    asm volatile("s_waitcnt lgkmcnt(0)" ::: "memory");
    __builtin_amdgcn_sched_barrier(0);
    __builtin_amdgcn_s_barrier();
    if (t + 2 < 16) ATTN_STAGE(cur, t + 2);
  }
#undef ATTN_STAGE
#pragma unroll
  for (int nq = 0; nq < 2; ++nq) {
    const float linv = 1.f / l_run[nq];
    const size_t tok = (size_t)(bb << 10) + q0 + nq * 16 + lr;
#pragma unroll
    for (int mb = 0; mb < 4; ++mb) {
      us4 o;
#pragma unroll
      for (int r = 0; r < 4; ++r) o[r] = f2bf(oacc[mb][nq][r] * linv);
      *(us4*)(O + tok * 768 + hh * 64 + mb * 16 + lg * 4) = o;
    }
  }
}

extern "C" void kernel_launch(void* const* d_in, const int* in_sizes, int n_in,
                              void* d_out, int out_size, void* d_ws, size_t ws_size,
                              hipStream_t stream) {
  const float* x      = (const float*)d_in[0];
  const float* ln1_g  = (const float*)d_in[1];
  const float* ln1_b  = (const float*)d_in[2];
  const float* qkv_w  = (const float*)d_in[3];
  const float* proj_w = (const float*)d_in[4];
  const float* proj_b = (const float*)d_in[5];
  const float* ln2_g  = (const float*)d_in[6];
  const float* ln2_b  = (const float*)d_in[7];
  const float* fc1_w  = (const float*)d_in[8];
  const float* fc1_b  = (const float*)d_in[9];
  const float* fc2_w  = (const float*)d_in[10];
  const float* fc2_b  = (const float*)d_in[11];
  float* out = (float*)d_out;
  char* ws = (char*)d_ws;

  unsigned short* wqkv = (unsigned short*)(ws + 0);
  unsigned short* wproj = (unsigned short*)(ws + 3538944);
  unsigned short* wfc1 = (unsigned short*)(ws + 4718592);
  unsigned short* wfc2 = (unsigned short*)(ws + 9437184);
  unsigned short* hbuf = (unsigned short*)(ws + 14155776);          // 16384x768 bf16
  char* big = ws + 39321600;                                        // 96 MB region
  unsigned short* qb  = (unsigned short*)(big);
  unsigned short* kb  = (unsigned short*)(big + 25165824);
  unsigned short* vtb = (unsigned short*)(big + 50331648);
  unsigned short* ob  = (unsigned short*)(big + 75497472);
  unsigned short* hid = (unsigned short*)(big);                     // reuses q/k/vt/o after attn+proj

  // weights -> bf16
  cvt_kernel<<<1728, 256, 0, stream>>>(qkv_w, wqkv, 442368);
  cvt_kernel<<<576, 256, 0, stream>>>(proj_w, wproj, 147456);
  cvt_kernel<<<2304, 256, 0, stream>>>(fc1_w, wfc1, 589824);
  cvt_kernel<<<2304, 256, 0, stream>>>(fc2_w, wfc2, 589824);

  // LN1
  ln_kernel<<<4096, 256, 0, stream>>>(x, ln1_g, ln1_b, hbuf);
  // QKV
  gemm8<0, 2304, 768><<<dim3(9, 64), 512, 0, stream>>>(
      hbuf, wqkv, nullptr, nullptr, nullptr, nullptr, qb, kb, vtb);
  // attention
  attn_kernel<<<dim3(8, 12, 16), 256, 0, stream>>>(qb, kb, vtb, ob);
  // proj + residual -> x1 (in d_out)
  gemm8<1, 768, 768><<<dim3(3, 64), 512, 0, stream>>>(
      ob, wproj, out, proj_b, x, nullptr, nullptr, nullptr, nullptr);
  // LN2
  ln_kernel<<<4096, 256, 0, stream>>>(out, ln2_g, ln2_b, hbuf);
  // FC1 + gelu
  gemm8<2, 3072, 768><<<dim3(12, 64), 512, 0, stream>>>(
      hbuf, wfc1, nullptr, fc1_b, nullptr, hid, nullptr, nullptr, nullptr);
  // FC2 + residual -> out
  gemm8<1, 768, 3072><<<dim3(3, 64), 512, 0, stream>>>(
      hid, wfc2, out, fc2_b, out, nullptr, nullptr, nullptr, nullptr);
}

// Round 11
// 472.156 us; speedup vs baseline: 1.2225x; 1.0965x over previous
//
#include <hip/hip_runtime.h>
#include <cstdint>
#include <cstddef>

typedef __attribute__((ext_vector_type(8))) short short8;
typedef __attribute__((ext_vector_type(4))) float f32x4;
typedef __attribute__((ext_vector_type(4))) unsigned short us4;

#define GAS(p) ((const __attribute__((address_space(1))) void*)(p))
#define LAS(p) ((__attribute__((address_space(3))) void*)(p))

__device__ __forceinline__ unsigned short f2bf(float f) {
  union { float f; unsigned u; } v; v.f = f;
  return (unsigned short)((v.u + 0x7fffu + ((v.u >> 16) & 1u)) >> 16);
}

// ---------- fp32 -> bf16 convert (x4 vectorized) ----------
__global__ __launch_bounds__(256) void cvt_kernel(const float* __restrict__ in,
                                                  unsigned short* __restrict__ out, int n4) {
  int i = blockIdx.x * 256 + threadIdx.x;
  if (i >= n4) return;
  f32x4 v = ((const f32x4*)in)[i];
  us4 o;
#pragma unroll
  for (int j = 0; j < 4; ++j) o[j] = f2bf(v[j]);
  ((us4*)out)[i] = o;
}

// ---------- LayerNorm: one wave per row of 768, bf16 out ----------
__global__ __launch_bounds__(256) void ln_kernel(const float* __restrict__ x,
                                                 const float* __restrict__ g,
                                                 const float* __restrict__ b,
                                                 unsigned short* __restrict__ out) {
  const int wave = threadIdx.x >> 6, lane = threadIdx.x & 63;
  const int row = blockIdx.x * 4 + wave;
  const float* xr = x + (size_t)row * 768;
  f32x4 v[3];
  float s = 0.f, sq = 0.f;
#pragma unroll
  for (int c = 0; c < 3; ++c) {
    v[c] = *(const f32x4*)(xr + c * 256 + lane * 4);
#pragma unroll
    for (int j = 0; j < 4; ++j) { s += v[c][j]; sq += v[c][j] * v[c][j]; }
  }
#pragma unroll
  for (int off = 32; off > 0; off >>= 1) { s += __shfl_xor(s, off); sq += __shfl_xor(sq, off); }
  const float mu = s * (1.f / 768.f);
  const float var = sq * (1.f / 768.f) - mu * mu;
  const float rs = rsqrtf(var + 1e-5f);
  unsigned short* orow = out + (size_t)row * 768;
#pragma unroll
  for (int c = 0; c < 3; ++c) {
    f32x4 gg = *(const f32x4*)(g + c * 256 + lane * 4);
    f32x4 bb = *(const f32x4*)(b + c * 256 + lane * 4);
    us4 o;
#pragma unroll
    for (int j = 0; j < 4; ++j) o[j] = f2bf((v[c][j] - mu) * rs * gg[j] + bb[j]);
    *(us4*)(orow + c * 256 + lane * 4) = o;
  }
}

// ---------- GEMM: C[M,NN] = A[M,K](bf16) @ W[NN,K]^T(bf16) ----------
// 16-wave (1024-thread) 256x256 tile: 4x4 wave grid, 64x64 output per wave
// -> acc = 64 AGPR -> ~120 regs total -> 4 waves/SIMD (the lever: with 2
// waves/SIMD every previous variant pinned at ~20% MfmaUtil; 4 waves let one
// wave's ds_reads overlap another's MFMAs). BK=32, FOUR LDS buffers (128 KB),
// ONE counted vmcnt + ONE barrier per K-tile, stage t+3 after the barrier.
// No lgkmcnt/sched_barrier pinning (compiler emits fine-grained waits).
// Publish rule (r9): per-wave vmcnt BEFORE the barrier that precedes reads.
// WAR safety: barrier(t) implies all waves' t-1 MFMAs done -> their ds_reads
// complete -> staging into buf[(t-1)&3] after barrier is safe.
// r5/r7-verified 0-conflict XOR swizzle (64B rows, chunk ^ (row>>1)&3).
// EPI 0: qkv scatter -> q (prescaled 0.125), k [B,H,N,64], vt [B,H,64,N]
// EPI 1: outF = acc + bias[col] + res[idx]   (fp32)
// EPI 2: outU = bf16(gelu_sigmoid(acc + bias[col]))
template <int EPI, int NN, int K>
__global__ __launch_bounds__(1024, 4) void gemmW(
    const unsigned short* __restrict__ A, const unsigned short* __restrict__ W,
    float* __restrict__ outF, const float* __restrict__ bias, const float* __restrict__ res,
    unsigned short* __restrict__ outU,
    unsigned short* __restrict__ q, unsigned short* __restrict__ kk, unsigned short* __restrict__ vt) {
  __shared__ unsigned short As[4][8192];   // [buf][256 rows x 32 ushorts (64B)]
  __shared__ unsigned short Bs[4][8192];
  const int tid = threadIdx.x;
  const int wave = tid >> 6, lane = tid & 63;
  const int lr = lane & 15, lg = lane >> 4;
  const int wr = wave >> 2, wc = wave & 3;     // 4M x 4N wave grid
  constexpr int GX = NN / 256;
  constexpr int NWG = GX * 64;                 // M=16384 -> 64 row tiles; NWG % 8 == 0
  int id = blockIdx.y * GX + blockIdx.x;
  id = (id & 7) * (NWG / 8) + (id >> 3);       // bijective XCD swizzle
  const int row0 = (id / GX) * 256, col0 = (id % GX) * 256;
  f32x4 acc[4][4] = {};
  // staging: thread t -> row t>>2, chunk t&3 (1024 threads cover 256 rows);
  // LDS dest linear (wave base + lane*16B); global chunk pre-swizzled
  // ^((t>>3)&3) so LDS[row][c] holds global chunk c ^ ((row>>1)&3)
  const int sc = ((tid & 3) ^ ((tid >> 3) & 3)) * 8;
  const unsigned short* ag = A + (size_t)(row0 + (tid >> 2)) * K + sc;
  const unsigned short* bg = W + (size_t)(col0 + (tid >> 2)) * K + sc;
  const int rsw = (lg ^ ((lr >> 1) & 3)) << 4; // read-side byte XOR within 64B row
  constexpr int KT = K / 32;                   // 24 or 96 (divisible by 4)

#define STG(buf, t_)                                                                           \
  {                                                                                            \
    __builtin_amdgcn_global_load_lds(GAS(ag + (t_) * 32), LAS(&As[buf][wave * 512]), 16, 0, 0);\
    __builtin_amdgcn_global_load_lds(GAS(bg + (t_) * 32), LAS(&Bs[buf][wave * 512]), 16, 0, 0);\
  }

#define TILE(buf, t_)                                                                          \
  {                                                                                            \
    if ((t_) < KT - 2)       { asm volatile("s_waitcnt vmcnt(4)" ::: "memory"); }              \
    else if ((t_) == KT - 2) { asm volatile("s_waitcnt vmcnt(2)" ::: "memory"); }              \
    else                     { asm volatile("s_waitcnt vmcnt(0)" ::: "memory"); }              \
    __builtin_amdgcn_s_barrier();                                                              \
    if ((t_) + 3 < KT) STG(((buf) + 3) & 3, (t_) + 3);                                         \
    const char* Ab = (const char*)As + (buf) * 16384;                                          \
    const char* Bb = (const char*)Bs + (buf) * 16384;                                          \
    short8 af[4], bfv[4];                                                                      \
    _Pragma("unroll")                                                                          \
    for (int m = 0; m < 4; ++m) {                                                              \
      const int arow = wr * 64 + m * 16 + lr;                                                  \
      af[m] = *(const short8*)(Ab + arow * 64 + rsw);                                          \
    }                                                                                          \
    _Pragma("unroll")                                                                          \
    for (int n = 0; n < 4; ++n) {                                                              \
      const int brow = wc * 64 + n * 16 + lr;                                                  \
      bfv[n] = *(const short8*)(Bb + brow * 64 + rsw);                                         \
    }                                                                                          \
    __builtin_amdgcn_s_setprio(1);                                                             \
    _Pragma("unroll")                                                                          \
    for (int m = 0; m < 4; ++m)                                                                \
      _Pragma("unroll")                                                                        \
      for (int n = 0; n < 4; ++n)                                                              \
        acc[m][n] = __builtin_amdgcn_mfma_f32_16x16x32_bf16(af[m], bfv[n], acc[m][n], 0, 0, 0);\
    __builtin_amdgcn_s_setprio(0);                                                             \
  }

  // prologue: stage tiles 0,1,2 (KT >= 4 always)
  STG(0, 0);
  STG(1, 1);
  STG(2, 2);
  for (int tt = 0; tt < KT; tt += 4) {
    TILE(0, tt);
    TILE(1, tt + 1);
    TILE(2, tt + 2);
    TILE(3, tt + 3);
  }
#undef TILE
#undef STG

  if (EPI == 0) {
    // segment is block-uniform: col tiles 256-wide, boundaries at 768/1536
    const int s = (col0 >= 1536) ? 2 : (col0 >= 768 ? 1 : 0);
    const int hh = (col0 + wc * 64 - s * 768) >> 6;
#pragma unroll
    for (int m = 0; m < 4; ++m)
#pragma unroll
      for (int n = 0; n < 4; ++n) {
        const int d = n * 16 + lr;
        const int g0 = row0 + wr * 64 + m * 16 + lg * 4;
        const int bt = g0 >> 10, nt0 = g0 & 1023;
        const size_t bh = (size_t)(bt * 12 + hh);
        if (s == 2) {
          us4 o;
#pragma unroll
          for (int r = 0; r < 4; ++r) o[r] = f2bf(acc[m][n][r]);
          *(us4*)(vt + (bh * 64 + d) * 1024 + nt0) = o;
        } else {
#pragma unroll
          for (int r = 0; r < 4; ++r) {
            const float val = acc[m][n][r];
            if (s == 0) q[(bh * 1024 + nt0 + r) * 64 + d] = f2bf(val * 0.125f);
            else        kk[(bh * 1024 + nt0 + r) * 64 + d] = f2bf(val);
          }
        }
      }
  } else if (EPI == 1) {
#pragma unroll
    for (int m = 0; m < 4; ++m)
#pragma unroll
      for (int n = 0; n < 4; ++n) {
        const int gcol = col0 + wc * 64 + n * 16 + lr;
        const float bn = bias[gcol];
#pragma unroll
        for (int r = 0; r < 4; ++r) {
          const int grow = row0 + wr * 64 + m * 16 + lg * 4 + r;
          const size_t idx = (size_t)grow * NN + gcol;
          outF[idx] = acc[m][n][r] + bn + res[idx];
        }
      }
  } else {
#pragma unroll
    for (int m = 0; m < 4; ++m)
#pragma unroll
      for (int n = 0; n < 4; ++n) {
        const int gcol = col0 + wc * 64 + n * 16 + lr;
        const float bn = bias[gcol];
#pragma unroll
        for (int r = 0; r < 4; ++r) {
          const int grow = row0 + wr * 64 + m * 16 + lg * 4 + r;
          const size_t idx = (size_t)grow * NN + gcol;
          const float t = acc[m][n][r] + bn;
          const float u = t * (1.59576912f + t * t * 0.07135481f);
          const float eu = __expf(-u);
          outU[idx] = f2bf(t / (1.f + eu));
        }
      }
  }
}

// ---------- Flash attention, swapped-operand (S^T / O^T), in-register softmax ----------
__global__ __launch_bounds__(256) void attn_kernel(
    const unsigned short* __restrict__ Q, const unsigned short* __restrict__ K,
    const unsigned short* __restrict__ V, unsigned short* __restrict__ O) {
  __shared__ unsigned short Ks[2][64 * 64];  // [kv][d], chunk-swizzled rows
  __shared__ unsigned short Vs[2][64 * 64];  // [d][kv], chunk-swizzled rows
  const int tid = threadIdx.x, wave = tid >> 6, lane = tid & 63;
  const int lr = lane & 15, lg = lane >> 4;
  const int qt = blockIdx.x, hh = blockIdx.y, bb = blockIdx.z;
  const size_t bh = (size_t)bb * 12 + hh;
  const unsigned short* Qg = Q + bh * 1024 * 64;
  const unsigned short* Kg = K + bh * 1024 * 64;
  const unsigned short* Vg = V + bh * 64 * 1024;
  const int q0 = qt * 128 + wave * 32;
  short8 aq[2][2];  // [nq][kb]
#pragma unroll
  for (int nq = 0; nq < 2; ++nq)
#pragma unroll
    for (int kb = 0; kb < 2; ++kb)
      aq[nq][kb] = *(const short8*)(Qg + (size_t)(q0 + nq * 16 + lr) * 64 + kb * 32 + lg * 8);
  float m_run[2] = {-1e30f, -1e30f}, l_run[2] = {0.f, 0.f};
  f32x4 oacc[4][2] = {};  // [mb over d][nq], O^T layout: col=q(lr), row=d
  const int srow = tid >> 3;
  const int sswz = (((tid & 7) * 16) ^ ((srow & 7) << 4)) >> 1;
  const int srcLo = (lane & 15) | ((lane & 16) << 1);
  const int srcHi = srcLo + 16;
  const bool hiSel = lg >= 2;
#define ATTN_STAGE(buf, t_)                                                                      \
  {                                                                                              \
    const int kv_ = (t_) * 64;                                                                   \
    _Pragma("unroll")                                                                            \
    for (int is = 0; is < 2; ++is) {                                                             \
      __builtin_amdgcn_global_load_lds(GAS(Kg + (size_t)(kv_ + is * 32 + srow) * 64 + sswz),     \
                                       LAS(&Ks[buf][is * 2048 + wave * 512]), 16, 0, 0);         \
      __builtin_amdgcn_global_load_lds(GAS(Vg + (size_t)(is * 32 + srow) * 1024 + kv_ + sswz),   \
                                       LAS(&Vs[buf][is * 2048 + wave * 512]), 16, 0, 0);         \
    }                                                                                            \
  }
  ATTN_STAGE(0, 0);
  ATTN_STAGE(1, 1);
  for (int t = 0; t < 16; ++t) {
    const int cur = t & 1;
    if (t < 15) asm volatile("s_waitcnt vmcnt(4)" ::: "memory");
    else        asm volatile("s_waitcnt vmcnt(0)" ::: "memory");
    __builtin_amdgcn_s_barrier();
    __builtin_amdgcn_sched_barrier(0);
    f32x4 sacc[4][2] = {};
#pragma unroll
    for (int kb = 0; kb < 2; ++kb) {
      short8 kf[4];
#pragma unroll
      for (int mk = 0; mk < 4; ++mk) {
        const int row = mk * 16 + lr;
        const int boff = row * 128 + ((kb * 64 + lg * 16) ^ ((row & 7) << 4));
        kf[mk] = *(const short8*)((const char*)&Ks[cur][0] + boff);
      }
#pragma unroll
      for (int mk = 0; mk < 4; ++mk)
#pragma unroll
        for (int nq = 0; nq < 2; ++nq)
          sacc[mk][nq] = __builtin_amdgcn_mfma_f32_16x16x32_bf16(kf[mk], aq[nq][kb], sacc[mk][nq], 0, 0, 0);
    }
    unsigned pk[4][2][2];
#pragma unroll
    for (int nq = 0; nq < 2; ++nq) {
      float mx = sacc[0][nq][0];
#pragma unroll
      for (int mk = 0; mk < 4; ++mk)
#pragma unroll
        for (int r = 0; r < 4; ++r) mx = fmaxf(mx, sacc[mk][nq][r]);
      mx = fmaxf(mx, __shfl_xor(mx, 16));
      mx = fmaxf(mx, __shfl_xor(mx, 32));
      const float mnew = fmaxf(m_run[nq], mx);
      const float alpha = __expf(m_run[nq] - mnew);
      float ssum = 0.f;
#pragma unroll
      for (int mk = 0; mk < 4; ++mk)
#pragma unroll
        for (int r = 0; r < 4; ++r) {
          const float p = __expf(sacc[mk][nq][r] - mnew);
          sacc[mk][nq][r] = p;
          ssum += p;
        }
      ssum += __shfl_xor(ssum, 16);
      ssum += __shfl_xor(ssum, 32);
      l_run[nq] = alpha * l_run[nq] + ssum;
      m_run[nq] = mnew;
#pragma unroll
      for (int mb = 0; mb < 4; ++mb)
#pragma unroll
        for (int r = 0; r < 4; ++r) oacc[mb][nq][r] *= alpha;
#pragma unroll
      for (int mk = 0; mk < 4; ++mk) {
        asm("v_cvt_pk_bf16_f32 %0, %1, %2" : "=v"(pk[mk][nq][0]) : "v"(sacc[mk][nq][0]), "v"(sacc[mk][nq][1]));
        asm("v_cvt_pk_bf16_f32 %0, %1, %2" : "=v"(pk[mk][nq][1]) : "v"(sacc[mk][nq][2]), "v"(sacc[mk][nq][3]));
      }
    }
#pragma unroll
    for (int kb = 0; kb < 2; ++kb) {
      short8 vf[4];
#pragma unroll
      for (int mb = 0; mb < 4; ++mb) {
        const int row = mb * 16 + lr;
        const int boff = row * 128 + ((kb * 64 + lg * 16) ^ ((row & 7) << 4));
        vf[mb] = *(const short8*)((const char*)&Vs[cur][0] + boff);
      }
#pragma unroll
      for (int nq = 0; nq < 2; ++nq) {
        unsigned a0 = (unsigned)__shfl((int)pk[2 * kb][nq][0], srcLo);
        unsigned b0 = (unsigned)__shfl((int)pk[2 * kb + 1][nq][0], srcLo);
        unsigned a1 = (unsigned)__shfl((int)pk[2 * kb][nq][1], srcLo);
        unsigned b1 = (unsigned)__shfl((int)pk[2 * kb + 1][nq][1], srcLo);
        unsigned a2 = (unsigned)__shfl((int)pk[2 * kb][nq][0], srcHi);
        unsigned b2 = (unsigned)__shfl((int)pk[2 * kb + 1][nq][0], srcHi);
        unsigned a3 = (unsigned)__shfl((int)pk[2 * kb][nq][1], srcHi);
        unsigned b3 = (unsigned)__shfl((int)pk[2 * kb + 1][nq][1], srcHi);
        union { unsigned u[4]; short8 s; } cvt;
        cvt.u[0] = hiSel ? b0 : a0;
        cvt.u[1] = hiSel ? b1 : a1;
        cvt.u[2] = hiSel ? b2 : a2;
        cvt.u[3] = hiSel ? b3 : a3;
        const short8 pb = cvt.s;
#pragma unroll
        for (int mb = 0; mb < 4; ++mb)
          oacc[mb][nq] = __builtin_amdgcn_mfma_f32_16x16x32_bf16(vf[mb], pb, oacc[mb][nq], 0, 0, 0);
      }
    }
    asm volatile("s_waitcnt lgkmcnt(0)" ::: "memory");
    __builtin_amdgcn_sched_barrier(0);
    __builtin_amdgcn_s_barrier();
    if (t + 2 < 16) ATTN_STAGE(cur, t + 2);
  }
#undef ATTN_STAGE
#pragma unroll
  for (int nq = 0; nq < 2; ++nq) {
    const float linv = 1.f / l_run[nq];
    const size_t tok = (size_t)(bb << 10) + q0 + nq * 16 + lr;
#pragma unroll
    for (int mb = 0; mb < 4; ++mb) {
      us4 o;
#pragma unroll
      for (int r = 0; r < 4; ++r) o[r] = f2bf(oacc[mb][nq][r] * linv);
      *(us4*)(O + tok * 768 + hh * 64 + mb * 16 + lg * 4) = o;
    }
  }
}

extern "C" void kernel_launch(void* const* d_in, const int* in_sizes, int n_in,
                              void* d_out, int out_size, void* d_ws, size_t ws_size,
                              hipStream_t stream) {
  const float* x      = (const float*)d_in[0];
  const float* ln1_g  = (const float*)d_in[1];
  const float* ln1_b  = (const float*)d_in[2];
  const float* qkv_w  = (const float*)d_in[3];
  const float* proj_w = (const float*)d_in[4];
  const float* proj_b = (const float*)d_in[5];
  const float* ln2_g  = (const float*)d_in[6];
  const float* ln2_b  = (const float*)d_in[7];
  const float* fc1_w  = (const float*)d_in[8];
  const float* fc1_b  = (const float*)d_in[9];
  const float* fc2_w  = (const float*)d_in[10];
  const float* fc2_b  = (const float*)d_in[11];
  float* out = (float*)d_out;
  char* ws = (char*)d_ws;

  unsigned short* wqkv = (unsigned short*)(ws + 0);
  unsigned short* wproj = (unsigned short*)(ws + 3538944);
  unsigned short* wfc1 = (unsigned short*)(ws + 4718592);
  unsigned short* wfc2 = (unsigned short*)(ws + 9437184);
  unsigned short* hbuf = (unsigned short*)(ws + 14155776);          // 16384x768 bf16
  char* big = ws + 39321600;                                        // 96 MB region
  unsigned short* qb  = (unsigned short*)(big);
  unsigned short* kb  = (unsigned short*)(big + 25165824);
  unsigned short* vtb = (unsigned short*)(big + 50331648);
  unsigned short* ob  = (unsigned short*)(big + 75497472);
  unsigned short* hid = (unsigned short*)(big);                     // reuses q/k/vt/o after attn+proj

  // weights -> bf16
  cvt_kernel<<<1728, 256, 0, stream>>>(qkv_w, wqkv, 442368);
  cvt_kernel<<<576, 256, 0, stream>>>(proj_w, wproj, 147456);
  cvt_kernel<<<2304, 256, 0, stream>>>(fc1_w, wfc1, 589824);
  cvt_kernel<<<2304, 256, 0, stream>>>(fc2_w, wfc2, 589824);

  // LN1
  ln_kernel<<<4096, 256, 0, stream>>>(x, ln1_g, ln1_b, hbuf);
  // QKV
  gemmW<0, 2304, 768><<<dim3(9, 64), 1024, 0, stream>>>(
      hbuf, wqkv, nullptr, nullptr, nullptr, nullptr, qb, kb, vtb);
  // attention
  attn_kernel<<<dim3(8, 12, 16), 256, 0, stream>>>(qb, kb, vtb, ob);
  // proj + residual -> x1 (in d_out)
  gemmW<1, 768, 768><<<dim3(3, 64), 1024, 0, stream>>>(
      ob, wproj, out, proj_b, x, nullptr, nullptr, nullptr, nullptr);
  // LN2
  ln_kernel<<<4096, 256, 0, stream>>>(out, ln2_g, ln2_b, hbuf);
  // FC1 + gelu
  gemmW<2, 3072, 768><<<dim3(12, 64), 1024, 0, stream>>>(
      hbuf, wfc1, nullptr, fc1_b, nullptr, hid, nullptr, nullptr, nullptr);
  // FC2 + residual -> out
  gemmW<1, 768, 3072><<<dim3(3, 64), 1024, 0, stream>>>(
      hid, wfc2, out, fc2_b, out, nullptr, nullptr, nullptr, nullptr);
}